// Round 1
// baseline (775.723 us; speedup 1.0000x reference)
//
#include <hip/hip_runtime.h>

#define TSEQ   2048
#define DMODEL 1024
#define NHEAD  16
#define DKDIM  64
#define BLKSZ  128
#define TBLK   16
#define SCALEF 0.125f   // TAU / sqrt(DK)

// ---- helpers -------------------------------------------------------------

// Read 8 consecutive logical elements [m8 .. m8+7] of row `row` from a
// [64][128] (or [128][128]) tile whose columns are stored XOR-swizzled by X
// (X is a multiple of 4 in bits 2..4, so each aligned float4 chunk stays
// contiguous; the two chunks live at c0 and c0^4).
__device__ __forceinline__ void read8(const float* __restrict__ T, int row, int m8, int X,
                                      float out[8]) {
  const int c0 = m8 ^ X;
  const float4 a = *reinterpret_cast<const float4*>(T + row * BLKSZ + c0);
  const float4 b = *reinterpret_cast<const float4*>(T + row * BLKSZ + (c0 ^ 4));
  out[0] = a.x; out[1] = a.y; out[2] = a.z; out[3] = a.w;
  out[4] = b.x; out[5] = b.y; out[6] = b.z; out[7] = b.w;
}

// Stage a 128x64 global tile (row stride DMODEL) into LDS transposed as
// T[d][r] (d-major), optionally column-swizzled: T[d][ r ^ ((d>>2 & 7)<<2) ].
// 256 threads, each loads 8 float4s (coalesced 16B/lane).
template <int SWZ>
__device__ __forceinline__ void stage_T(float* __restrict__ T, const float* __restrict__ g,
                                        int tid, float scale) {
#pragma unroll
  for (int it = 0; it < 8; ++it) {
    const int idx = tid + 256 * it;   // float4 index 0..2047
    const int r  = idx >> 4;          // 0..127
    const int d4 = idx & 15;          // 0..15  (d = 4*d4+k)
    const float4 vv = *reinterpret_cast<const float4*>(g + r * DMODEL + 4 * d4);
    const int colr = SWZ ? (r ^ ((d4 & 7) << 2)) : r;  // (4d4+k)>>2 == d4 for k<4
    float* p = T + (4 * d4) * BLKSZ + colr;
    p[0 * BLKSZ] = vv.x * scale;
    p[1 * BLKSZ] = vv.y * scale;
    p[2 * BLKSZ] = vv.z * scale;
    p[3 * BLKSZ] = vv.w * scale;
  }
}

#define SHFL_MAX16(x)  { x = fmaxf(x, __shfl_xor(x, 1)); x = fmaxf(x, __shfl_xor(x, 2)); \
                         x = fmaxf(x, __shfl_xor(x, 4)); x = fmaxf(x, __shfl_xor(x, 8)); }
#define SHFL_SUM16(x)  { x += __shfl_xor(x, 1); x += __shfl_xor(x, 2); \
                         x += __shfl_xor(x, 4); x += __shfl_xor(x, 8); }

// ---- kernel 1: dQ --------------------------------------------------------
// grid = (h, i) = 256 wgs; per wg loop over active j.
// dQ_i = sum_j dS_ij @ k_j * scale   (k pre-scaled at staging)
__global__ void __launch_bounds__(256, 1)
k1_dq(const float* __restrict__ q, const float* __restrict__ kk,
      const float* __restrict__ v, const float* __restrict__ dOg,
      const int* __restrict__ mask, float* __restrict__ dQ) {
  __shared__ float sA[2 * DKDIM * BLKSZ];  // qT | dOT ; reused as dSt[128][128]
  __shared__ float sB[2 * DKDIM * BLKSZ];  // kT(swz,*scale) | vT
  const int tid = threadIdx.x;
  const int h = blockIdx.x >> 4, ib = blockIdx.x & 15;
  const int tr = tid >> 4, tc = tid & 15;
  const float* qp = q   + (ib * BLKSZ) * DMODEL + h * DKDIM;
  const float* op = dOg + (ib * BLKSZ) * DMODEL + h * DKDIM;

  float accQ[8][4] = {};

  for (int j = 0; j < TBLK; ++j) {
    if (mask[ib * TBLK + j] == 0) continue;
    stage_T<0>(sA,                 qp, tid, 1.0f);
    stage_T<0>(sA + DKDIM * BLKSZ, op, tid, 1.0f);
    stage_T<1>(sB,                 kk + (j * BLKSZ) * DMODEL + h * DKDIM, tid, SCALEF);
    stage_T<0>(sB + DKDIM * BLKSZ, v  + (j * BLKSZ) * DMODEL + h * DKDIM, tid, 1.0f);
    __syncthreads();

    // S[a][b] for rows 8tr+a, cols 8tc+b (already scaled via k)
    float P[8][8] = {};
#pragma unroll 2
    for (int d = 0; d < DKDIM; ++d) {
      float qv[8], kv[8];
      read8(sA, d, 8 * tr, 0, qv);
      read8(sB, d, 8 * tc, ((d >> 2) & 7) << 2, kv);
#pragma unroll
      for (int a = 0; a < 8; ++a)
#pragma unroll
        for (int b = 0; b < 8; ++b) P[a][b] += qv[a] * kv[b];
    }

    // local (per-block) softmax over the 128 cols
#pragma unroll
    for (int a = 0; a < 8; ++a) {
      float mm = P[a][0];
#pragma unroll
      for (int b = 1; b < 8; ++b) mm = fmaxf(mm, P[a][b]);
      SHFL_MAX16(mm);
      float ss = 0.f;
#pragma unroll
      for (int b = 0; b < 8; ++b) { P[a][b] = __expf(P[a][b] - mm); ss += P[a][b]; }
      SHFL_SUM16(ss);
      const float inv = 1.f / (ss + 1e-12f);
#pragma unroll
      for (int b = 0; b < 8; ++b) P[a][b] *= inv;
    }

    // dA = dO_i @ v_j^T
    float dS[8][8] = {};
#pragma unroll 2
    for (int d = 0; d < DKDIM; ++d) {
      float ov[8], vv[8];
      read8(sA + DKDIM * BLKSZ, d, 8 * tr, 0, ov);
      read8(sB + DKDIM * BLKSZ, d, 8 * tc, 0, vv);
#pragma unroll
      for (int a = 0; a < 8; ++a)
#pragma unroll
        for (int b = 0; b < 8; ++b) dS[a][b] += ov[a] * vv[b];
    }

    // dS = Pn * (dA - rowdot)
#pragma unroll
    for (int a = 0; a < 8; ++a) {
      float rd = 0.f;
#pragma unroll
      for (int b = 0; b < 8; ++b) rd += P[a][b] * dS[a][b];
      SHFL_SUM16(rd);
#pragma unroll
      for (int b = 0; b < 8; ++b) dS[a][b] = P[a][b] * (dS[a][b] - rd);
    }
    __syncthreads();  // all waves done reading qT/dOT (sA) before overwrite

    // materialize dSt[c][r] over sA
#pragma unroll
    for (int b = 0; b < 8; ++b) {
      const int c = 8 * tc + b;
      float4 w0 = make_float4(dS[0][b], dS[1][b], dS[2][b], dS[3][b]);
      float4 w1 = make_float4(dS[4][b], dS[5][b], dS[6][b], dS[7][b]);
      *reinterpret_cast<float4*>(sA + c * BLKSZ + 8 * tr)     = w0;
      *reinterpret_cast<float4*>(sA + c * BLKSZ + 8 * tr + 4) = w1;
    }
    __syncthreads();

    // dQ[8tr+a][4tc+dd] += sum_c dSt[c][8tr+a] * kT[4tc+dd][c]
    const int Xc = (tc & 7) << 2;
#pragma unroll 4
    for (int c = 0; c < BLKSZ; ++c) {
      float dsv[8];
      read8(sA, c, 8 * tr, 0, dsv);
      float kx[4];
#pragma unroll
      for (int dd = 0; dd < 4; ++dd) kx[dd] = sB[(4 * tc + dd) * BLKSZ + (c ^ Xc)];
#pragma unroll
      for (int a = 0; a < 8; ++a)
#pragma unroll
        for (int dd = 0; dd < 4; ++dd) accQ[a][dd] += dsv[a] * kx[dd];
    }
    __syncthreads();  // before next j restages
  }

#pragma unroll
  for (int a = 0; a < 8; ++a) {
    float4 w = make_float4(accQ[a][0], accQ[a][1], accQ[a][2], accQ[a][3]);
    *reinterpret_cast<float4*>(dQ + (ib * BLKSZ + 8 * tr + a) * DMODEL + h * DKDIM + 4 * tc) = w;
  }
}

// ---- kernel 2: dK, dV ----------------------------------------------------
// grid = (h, j) = 256 wgs; per wg loop over active i.
// dK_j = sum_i dS_ij^T @ q_i * scale   (q pre-scaled)
// dV_j = sum_i Pn_ij^T @ dO_i
__global__ void __launch_bounds__(256, 1)
k2_dkv(const float* __restrict__ q, const float* __restrict__ kk,
       const float* __restrict__ v, const float* __restrict__ dOg,
       const int* __restrict__ mask, float* __restrict__ dK, float* __restrict__ dV) {
  __shared__ float s1[2 * DKDIM * BLKSZ];  // qT(swz,*scale) | dOT(swz)
  __shared__ float s2[2 * DKDIM * BLKSZ];  // kT | vT -> Pn_r[128][128] -> dS_r[128][128]
  const int tid = threadIdx.x;
  const int h = blockIdx.x >> 4, jb = blockIdx.x & 15;
  const int tr = tid >> 4, tc = tid & 15;
  const float* kp = kk + (jb * BLKSZ) * DMODEL + h * DKDIM;
  const float* vp = v  + (jb * BLKSZ) * DMODEL + h * DKDIM;

  float accK[8][4] = {}, accV[8][4] = {};

  for (int i = 0; i < TBLK; ++i) {
    if (mask[i * TBLK + jb] == 0) continue;
    stage_T<1>(s1,                 q   + (i * BLKSZ) * DMODEL + h * DKDIM, tid, SCALEF);
    stage_T<1>(s1 + DKDIM * BLKSZ, dOg + (i * BLKSZ) * DMODEL + h * DKDIM, tid, 1.0f);
    stage_T<0>(s2,                 kp, tid, 1.0f);
    stage_T<0>(s2 + DKDIM * BLKSZ, vp, tid, 1.0f);
    __syncthreads();

    float P[8][8] = {};
#pragma unroll 2
    for (int d = 0; d < DKDIM; ++d) {
      float qv[8], kv[8];
      read8(s1, d, 8 * tr, ((d >> 2) & 7) << 2, qv);
      read8(s2, d, 8 * tc, 0, kv);
#pragma unroll
      for (int a = 0; a < 8; ++a)
#pragma unroll
        for (int b = 0; b < 8; ++b) P[a][b] += qv[a] * kv[b];
    }

#pragma unroll
    for (int a = 0; a < 8; ++a) {
      float mm = P[a][0];
#pragma unroll
      for (int b = 1; b < 8; ++b) mm = fmaxf(mm, P[a][b]);
      SHFL_MAX16(mm);
      float ss = 0.f;
#pragma unroll
      for (int b = 0; b < 8; ++b) { P[a][b] = __expf(P[a][b] - mm); ss += P[a][b]; }
      SHFL_SUM16(ss);
      const float inv = 1.f / (ss + 1e-12f);
#pragma unroll
      for (int b = 0; b < 8; ++b) P[a][b] *= inv;
    }

    float dS[8][8] = {};
#pragma unroll 2
    for (int d = 0; d < DKDIM; ++d) {
      float ov[8], vv[8];
      read8(s1 + DKDIM * BLKSZ, d, 8 * tr, ((d >> 2) & 7) << 2, ov);
      read8(s2 + DKDIM * BLKSZ, d, 8 * tc, 0, vv);
#pragma unroll
      for (int a = 0; a < 8; ++a)
#pragma unroll
        for (int b = 0; b < 8; ++b) dS[a][b] += ov[a] * vv[b];
    }

#pragma unroll
    for (int a = 0; a < 8; ++a) {
      float rd = 0.f;
#pragma unroll
      for (int b = 0; b < 8; ++b) rd += P[a][b] * dS[a][b];
      SHFL_SUM16(rd);
#pragma unroll
      for (int b = 0; b < 8; ++b) dS[a][b] = P[a][b] * (dS[a][b] - rd);
    }
    __syncthreads();  // all waves done with kT/vT (s2)

    // Pn row-major over s2
#pragma unroll
    for (int a = 0; a < 8; ++a) {
      const int r = 8 * tr + a;
      *reinterpret_cast<float4*>(s2 + r * BLKSZ + 8 * tc)     = make_float4(P[a][0], P[a][1], P[a][2], P[a][3]);
      *reinterpret_cast<float4*>(s2 + r * BLKSZ + 8 * tc + 4) = make_float4(P[a][4], P[a][5], P[a][6], P[a][7]);
    }
    __syncthreads();

    const int Xc = (tc & 7) << 2;
    // dV[8tr+a][4tc+dd] += sum_r Pn[r][8tr+a] * dOT[4tc+dd][r]
#pragma unroll 4
    for (int r = 0; r < BLKSZ; ++r) {
      float pv[8];
      read8(s2, r, 8 * tr, 0, pv);
      float ov[4];
#pragma unroll
      for (int dd = 0; dd < 4; ++dd)
        ov[dd] = s1[DKDIM * BLKSZ + (4 * tc + dd) * BLKSZ + (r ^ Xc)];
#pragma unroll
      for (int a = 0; a < 8; ++a)
#pragma unroll
        for (int dd = 0; dd < 4; ++dd) accV[a][dd] += pv[a] * ov[dd];
    }
    __syncthreads();

    // dS row-major over s2
#pragma unroll
    for (int a = 0; a < 8; ++a) {
      const int r = 8 * tr + a;
      *reinterpret_cast<float4*>(s2 + r * BLKSZ + 8 * tc)     = make_float4(dS[a][0], dS[a][1], dS[a][2], dS[a][3]);
      *reinterpret_cast<float4*>(s2 + r * BLKSZ + 8 * tc + 4) = make_float4(dS[a][4], dS[a][5], dS[a][6], dS[a][7]);
    }
    __syncthreads();

    // dK[8tr+a][4tc+dd] += sum_r dS[r][8tr+a] * qT[4tc+dd][r]  (q pre-scaled)
#pragma unroll 4
    for (int r = 0; r < BLKSZ; ++r) {
      float sv[8];
      read8(s2, r, 8 * tr, 0, sv);
      float qx[4];
#pragma unroll
      for (int dd = 0; dd < 4; ++dd)
        qx[dd] = s1[(4 * tc + dd) * BLKSZ + (r ^ Xc)];
#pragma unroll
      for (int a = 0; a < 8; ++a)
#pragma unroll
        for (int dd = 0; dd < 4; ++dd) accK[a][dd] += sv[a] * qx[dd];
    }
    __syncthreads();
  }

#pragma unroll
  for (int a = 0; a < 8; ++a) {
    const int row = (jb * BLKSZ + 8 * tr + a) * DMODEL + h * DKDIM + 4 * tc;
    *reinterpret_cast<float4*>(dK + row) = make_float4(accK[a][0], accK[a][1], accK[a][2], accK[a][3]);
    *reinterpret_cast<float4*>(dV + row) = make_float4(accV[a][0], accV[a][1], accV[a][2], accV[a][3]);
  }
}

// ---- launch --------------------------------------------------------------
extern "C" void kernel_launch(void* const* d_in, const int* in_sizes, int n_in,
                              void* d_out, int out_size, void* d_ws, size_t ws_size,
                              hipStream_t stream) {
  const float* q  = (const float*)d_in[0];
  const float* k  = (const float*)d_in[1];
  const float* v  = (const float*)d_in[2];
  const float* dO = (const float*)d_in[3];
  const int* mask = (const int*)d_in[4];
  float* out = (float*)d_out;
  float* dQ = out;
  float* dK = out + (size_t)TSEQ * DMODEL;
  float* dV = out + (size_t)2 * TSEQ * DMODEL;

  k1_dq <<<NHEAD * TBLK, 256, 0, stream>>>(q, k, v, dO, mask, dQ);
  k2_dkv<<<NHEAD * TBLK, 256, 0, stream>>>(q, k, v, dO, mask, dK, dV);
}

// Round 2
// 120.813 us; speedup vs baseline: 6.4209x; 6.4209x over previous
//
#include <hip/hip_runtime.h>

#define DMODEL 1024
#define NHEAD  16
#define DKD    64
#define BLK    128
#define TB     16
#define SCALEF 0.125f   // TAU / sqrt(DK)

typedef __attribute__((ext_vector_type(8))) short bf16x8;   // 8 bf16 in 4 VGPRs
typedef __attribute__((ext_vector_type(4))) float f32x4;

#define MFMA16(A, B, C) __builtin_amdgcn_mfma_f32_16x16x32_bf16(A, B, C, 0, 0, 0)

// fp32 -> bf16 RNE
__device__ __forceinline__ ushort bfc(float x) {
  union { float f; unsigned u; } c; c.f = x;
  const unsigned u = c.u;
  return (ushort)((u + 0x7FFFu + ((u >> 16) & 1u)) >> 16);
}

// Fragment read: 8 consecutive K-elems of row r starting at col c from a tile
// with row stride st (elems), XOR-swizzled by ((r&7)<<3) elems (bits 3-5).
__device__ __forceinline__ bf16x8 frag(const ushort* T, int r, int c, int st) {
  return *reinterpret_cast<const bf16x8*>(T + ((r * st + c) ^ ((r & 7) << 3)));
}

// Stage 128x64 global fp32 tile (row stride DMODEL) -> LDS bf16 row tile
// [128][64], swizzled. 512 threads, 4 iters, b64 LDS writes (conflict-free).
__device__ __forceinline__ void stageR(ushort* T, const float* __restrict__ g,
                                       float sc, int tid) {
#pragma unroll
  for (int it = 0; it < 4; ++it) {
    const int idx = tid + 512 * it;
    const int r = idx >> 4, d4 = idx & 15;
    const float4 f = *reinterpret_cast<const float4*>(g + r * DMODEL + 4 * d4);
    ushort4 u;
    u.x = bfc(f.x * sc); u.y = bfc(f.y * sc); u.z = bfc(f.z * sc); u.w = bfc(f.w * sc);
    *reinterpret_cast<ushort4*>(T + ((r * 64 + 4 * d4) ^ ((r & 7) << 3))) = u;
  }
}

// Stage transposed: global [128][64] slice -> LDS bf16 [64][128] (d-major),
// swizzled. Pairs rows so writes are b32.
__device__ __forceinline__ void stageT(ushort* T, const float* __restrict__ g,
                                       float sc, int tid) {
#pragma unroll
  for (int it = 0; it < 2; ++it) {
    const int idx = tid + 512 * it;
    const int rp = idx >> 4, d4 = idx & 15;
    const float4 fa = *reinterpret_cast<const float4*>(g + (2 * rp) * DMODEL + 4 * d4);
    const float4 fb = *reinterpret_cast<const float4*>(g + (2 * rp + 1) * DMODEL + 4 * d4);
    const float a4[4] = {fa.x, fa.y, fa.z, fa.w};
    const float b4[4] = {fb.x, fb.y, fb.z, fb.w};
#pragma unroll
    for (int kkk = 0; kkk < 4; ++kkk) {
      const int d = 4 * d4 + kkk;
      ushort2 u; u.x = bfc(a4[kkk] * sc); u.y = bfc(b4[kkk] * sc);
      *reinterpret_cast<ushort2*>(T + ((d * 128 + 2 * rp) ^ ((d & 7) << 3))) = u;
    }
  }
}

// LDS element offsets (ushort units), total 96 KB:
//  role 0 (dQ):  q=0  dO=8192  k=16384  v=24576  kT=32768..40960 ; dS over [16384,32768)
//  role 1 (dKV): k=0  v=8192   q=16384  dO=24576 qT=32768 dOT=40960 ; ST over [16384,32768)
__global__ void __launch_bounds__(512, 2)
bwd_all(const float* __restrict__ q, const float* __restrict__ kk,
        const float* __restrict__ v, const float* __restrict__ dOg,
        const int* __restrict__ mask,
        float* __restrict__ dQ, float* __restrict__ dK, float* __restrict__ dV) {
  __shared__ ushort sm[49152];
  const int tid = threadIdx.x;
  const int w = tid >> 6, l = tid & 63;
  const int l15 = l & 15, lg = l >> 4;
  const int pw = w * 16;
  const int bid = blockIdx.x;
  const int role = bid >> 8;
  const int h = (bid >> 4) & 15;
  const int blk = bid & 15;
  const f32x4 zz = {0.f, 0.f, 0.f, 0.f};

  if (role == 0) {
    // ---- dQ for (h, ib=blk): loop over active j ----
    const float* gq = q   + (size_t)(blk * BLK) * DMODEL + h * DKD;
    const float* go = dOg + (size_t)(blk * BLK) * DMODEL + h * DKD;
    stageR(sm + 0,    gq, 1.f, tid);
    stageR(sm + 8192, go, 1.f, tid);
    f32x4 accQ[4] = {zz, zz, zz, zz};

    for (int j = 0; j < TB; ++j) {
      if (!mask[blk * TB + j]) continue;
      const float* gk = kk + (size_t)(j * BLK) * DMODEL + h * DKD;
      const float* gv = v  + (size_t)(j * BLK) * DMODEL + h * DKD;
      stageR(sm + 16384, gk, SCALEF, tid);
      stageR(sm + 24576, gv, 1.f, tid);
      stageT(sm + 32768, gk, SCALEF, tid);
      __syncthreads();

      // S^T = k.q^T, dA^T = v.dO^T  (M = c rows, N = p cols; wave owns p-slice)
      // lane holds S[p = pw+l15][c = mf*16 + lg*4 + r]
      f32x4 ST[8]  = {zz, zz, zz, zz, zz, zz, zz, zz};
      f32x4 dAT[8] = {zz, zz, zz, zz, zz, zz, zz, zz};
#pragma unroll
      for (int kb = 0; kb < 2; ++kb) {
        const int c = kb * 32 + lg * 8;
        const bf16x8 bq = frag(sm + 0,    pw + l15, c, 64);
        const bf16x8 bo = frag(sm + 8192, pw + l15, c, 64);
#pragma unroll
        for (int mf = 0; mf < 8; ++mf) {
          ST[mf]  = MFMA16(frag(sm + 16384, mf * 16 + l15, c, 64), bq, ST[mf]);
          dAT[mf] = MFMA16(frag(sm + 24576, mf * 16 + l15, c, 64), bo, dAT[mf]);
        }
      }

      // per-p softmax over all 128 c (32 regs + lanes l^16, l^32)
      float mx = -1e30f;
#pragma unroll
      for (int mf = 0; mf < 8; ++mf)
#pragma unroll
        for (int r = 0; r < 4; ++r) mx = fmaxf(mx, ST[mf][r]);
      mx = fmaxf(mx, __shfl_xor(mx, 16));
      mx = fmaxf(mx, __shfl_xor(mx, 32));
      float ss = 0.f;
#pragma unroll
      for (int mf = 0; mf < 8; ++mf)
#pragma unroll
        for (int r = 0; r < 4; ++r) { const float e = __expf(ST[mf][r] - mx); ST[mf][r] = e; ss += e; }
      ss += __shfl_xor(ss, 16);
      ss += __shfl_xor(ss, 32);
      const float inv = 1.f / (ss + 1e-12f);
      float rd = 0.f;
#pragma unroll
      for (int mf = 0; mf < 8; ++mf)
#pragma unroll
        for (int r = 0; r < 4; ++r) { const float pn = ST[mf][r] * inv; ST[mf][r] = pn; rd += pn * dAT[mf][r]; }
      rd += __shfl_xor(rd, 16);
      rd += __shfl_xor(rd, 32);
#pragma unroll
      for (int mf = 0; mf < 8; ++mf)
#pragma unroll
        for (int r = 0; r < 4; ++r) dAT[mf][r] = ST[mf][r] * (dAT[mf][r] - rd);

      __syncthreads();  // all waves done reading k,v row tiles

      // write dS row-major [p][c] (stride 128) over k,v region; b64-packed
      const int p = pw + l15;
#pragma unroll
      for (int mf = 0; mf < 8; ++mf) {
        ushort4 u;
        u.x = bfc(dAT[mf][0]); u.y = bfc(dAT[mf][1]);
        u.z = bfc(dAT[mf][2]); u.w = bfc(dAT[mf][3]);
        *reinterpret_cast<ushort4*>(
            sm + 16384 + ((p * 128 + mf * 16 + lg * 4) ^ ((p & 7) << 3))) = u;
      }
      __syncthreads();

      // dQ += dS @ k  (A = dS[p][c], B = kT[d][c]); acc over j in regs
#pragma unroll
      for (int kb = 0; kb < 4; ++kb) {
        const int c = kb * 32 + lg * 8;
        const bf16x8 a = frag(sm + 16384, pw + l15, c, 128);
#pragma unroll
        for (int nf = 0; nf < 4; ++nf)
          accQ[nf] = MFMA16(a, frag(sm + 32768, nf * 16 + l15, c, 128), accQ[nf]);
      }
      __syncthreads();  // before next j restages k,v,kT
    }

#pragma unroll
    for (int nf = 0; nf < 4; ++nf)
#pragma unroll
      for (int r = 0; r < 4; ++r)
        dQ[(size_t)(blk * BLK + pw + lg * 4 + r) * DMODEL + h * DKD + nf * 16 + l15] =
            accQ[nf][r];

  } else {
    // ---- dK,dV for (h, jb=blk): loop over active i ----
    const int jb = blk;
    stageR(sm + 0,    kk + (size_t)(jb * BLK) * DMODEL + h * DKD, 1.f, tid);
    stageR(sm + 8192, v  + (size_t)(jb * BLK) * DMODEL + h * DKD, 1.f, tid);
    f32x4 accK[4] = {zz, zz, zz, zz};
    f32x4 accV[4] = {zz, zz, zz, zz};

    for (int i = 0; i < TB; ++i) {
      if (!mask[i * TB + jb]) continue;
      const float* gq = q   + (size_t)(i * BLK) * DMODEL + h * DKD;
      const float* go = dOg + (size_t)(i * BLK) * DMODEL + h * DKD;
      stageR(sm + 16384, gq, SCALEF, tid);
      stageR(sm + 24576, go, 1.f, tid);
      stageT(sm + 32768, gq, SCALEF, tid);
      stageT(sm + 40960, go, 1.f, tid);
      __syncthreads();

      // S = q.k^T, dA = dO.v^T  (M = p rows; wave owns p-slice, N_rep = 8)
      // lane holds S[p = pw + lg*4 + r][c = nf*16 + l15]
      f32x4 S[8]  = {zz, zz, zz, zz, zz, zz, zz, zz};
      f32x4 dA[8] = {zz, zz, zz, zz, zz, zz, zz, zz};
#pragma unroll
      for (int kb = 0; kb < 2; ++kb) {
        const int c = kb * 32 + lg * 8;
        const bf16x8 aq = frag(sm + 16384, pw + l15, c, 64);
        const bf16x8 ao = frag(sm + 24576, pw + l15, c, 64);
#pragma unroll
        for (int nf = 0; nf < 8; ++nf) {
          S[nf]  = MFMA16(aq, frag(sm + 0,    nf * 16 + l15, c, 64), S[nf]);
          dA[nf] = MFMA16(ao, frag(sm + 8192, nf * 16 + l15, c, 64), dA[nf]);
        }
      }

      // softmax per r (row p), reduce over c: 8 regs + lanes l^1,2,4,8
#pragma unroll
      for (int r = 0; r < 4; ++r) {
        float mx = -1e30f;
#pragma unroll
        for (int nf = 0; nf < 8; ++nf) mx = fmaxf(mx, S[nf][r]);
        mx = fmaxf(mx, __shfl_xor(mx, 1));
        mx = fmaxf(mx, __shfl_xor(mx, 2));
        mx = fmaxf(mx, __shfl_xor(mx, 4));
        mx = fmaxf(mx, __shfl_xor(mx, 8));
        float ss = 0.f;
#pragma unroll
        for (int nf = 0; nf < 8; ++nf) { const float e = __expf(S[nf][r] - mx); S[nf][r] = e; ss += e; }
        ss += __shfl_xor(ss, 1);
        ss += __shfl_xor(ss, 2);
        ss += __shfl_xor(ss, 4);
        ss += __shfl_xor(ss, 8);
        const float inv = 1.f / (ss + 1e-12f);
        float rd = 0.f;
#pragma unroll
        for (int nf = 0; nf < 8; ++nf) { const float pn = S[nf][r] * inv; S[nf][r] = pn; rd += pn * dA[nf][r]; }
        rd += __shfl_xor(rd, 1);
        rd += __shfl_xor(rd, 2);
        rd += __shfl_xor(rd, 4);
        rd += __shfl_xor(rd, 8);
#pragma unroll
        for (int nf = 0; nf < 8; ++nf) dA[nf][r] = S[nf][r] * (dA[nf][r] - rd);
      }

      __syncthreads();  // all waves done reading q,dO row tiles

      // write PnT [c][p] (stride 128) over q,dO region; b64-packed
#pragma unroll
      for (int nf = 0; nf < 8; ++nf) {
        const int c = nf * 16 + l15;
        ushort4 u;
        u.x = bfc(S[nf][0]); u.y = bfc(S[nf][1]); u.z = bfc(S[nf][2]); u.w = bfc(S[nf][3]);
        *reinterpret_cast<ushort4*>(
            sm + 16384 + ((c * 128 + pw + lg * 4) ^ ((c & 7) << 3))) = u;
      }
      __syncthreads();

      // dV += Pn^T @ dO  (A = PnT[c][p], B = dOT[d][p])
#pragma unroll
      for (int kb = 0; kb < 4; ++kb) {
        const int c = kb * 32 + lg * 8;
        const bf16x8 a = frag(sm + 16384, pw + l15, c, 128);
#pragma unroll
        for (int nf = 0; nf < 4; ++nf)
          accV[nf] = MFMA16(a, frag(sm + 40960, nf * 16 + l15, c, 128), accV[nf]);
      }
      __syncthreads();

      // write dST [c][p] same buffer
#pragma unroll
      for (int nf = 0; nf < 8; ++nf) {
        const int c = nf * 16 + l15;
        ushort4 u;
        u.x = bfc(dA[nf][0]); u.y = bfc(dA[nf][1]); u.z = bfc(dA[nf][2]); u.w = bfc(dA[nf][3]);
        *reinterpret_cast<ushort4*>(
            sm + 16384 + ((c * 128 + pw + lg * 4) ^ ((c & 7) << 3))) = u;
      }
      __syncthreads();

      // dK += dS^T @ q  (A = dST[c][p], B = qT[d][p]; q pre-scaled)
#pragma unroll
      for (int kb = 0; kb < 4; ++kb) {
        const int c = kb * 32 + lg * 8;
        const bf16x8 a = frag(sm + 16384, pw + l15, c, 128);
#pragma unroll
        for (int nf = 0; nf < 4; ++nf)
          accK[nf] = MFMA16(a, frag(sm + 32768, nf * 16 + l15, c, 128), accK[nf]);
      }
      __syncthreads();  // before next i restages q,dO,qT,dOT
    }

#pragma unroll
    for (int nf = 0; nf < 4; ++nf)
#pragma unroll
      for (int r = 0; r < 4; ++r) {
        const size_t row = (size_t)(jb * BLK + pw + lg * 4 + r) * DMODEL + h * DKD + nf * 16 + l15;
        dK[row] = accK[nf][r];
        dV[row] = accV[nf][r];
      }
  }
}

extern "C" void kernel_launch(void* const* d_in, const int* in_sizes, int n_in,
                              void* d_out, int out_size, void* d_ws, size_t ws_size,
                              hipStream_t stream) {
  const float* q  = (const float*)d_in[0];
  const float* k  = (const float*)d_in[1];
  const float* v  = (const float*)d_in[2];
  const float* dO = (const float*)d_in[3];
  const int* mask = (const int*)d_in[4];
  float* out = (float*)d_out;
  float* dQ = out;
  float* dK = out + (size_t)2048 * DMODEL;
  float* dV = out + (size_t)2 * 2048 * DMODEL;

  bwd_all<<<2 * NHEAD * TB, 512, 0, stream>>>(q, k, v, dO, mask, dQ, dK, dV);
}